// Round 10
// baseline (226.874 us; speedup 1.0000x reference)
//
#include <hip/hip_runtime.h>
#include <stdint.h>

// ---------------------------------------------------------------------------
// SingleHeadedAttention (Mega-style, laplacian attn fn, causal, T5 rel bias)
// B=4, S=2048, DIM=1024, DQK=128, DV=1024.  fp32 in/out, bf16 MFMA internals.
// R10: R9 (tiled layouts + register-pipeline GEMMs, no LDS/barriers) plus:
//   (1) branchless inline fast-erf in k_gemm_sim (A&S 7.1.26) replacing the
//       branchy ocml erff — sim had 8x less GEMM work than qkv yet ran
//       slower; erf is the only extra ingredient.
//   (2) k_prep_x: linear coalesced reads + scattered tiled writes (was
//       lane-stride-4KB read gather).
//   TILED: element (row,k) of [R][K] at
//     ((row>>4)*(K>>5) + (k>>5))*512 + ((k>>3)&3)*128 + (row&15)*8 + (k&7).
// ---------------------------------------------------------------------------

#define B_   4
#define S_   2048
#define DIM_ 1024
#define DQK  128
#define DV   1024
#define NQV  1152

typedef __attribute__((ext_vector_type(8))) short short8;   // 8 bf16
typedef __attribute__((ext_vector_type(4))) float f32x4;    // MFMA C/D

__device__ __forceinline__ uint16_t f32_to_bf16(float f) {
  uint32_t u = __float_as_uint(f);
  u += 0x7FFFu + ((u >> 16) & 1u);          // round-to-nearest-even
  return (uint16_t)(u >> 16);
}

__device__ __forceinline__ float silu_f(float x) {
  return x / (1.0f + __expf(-x));
}

// 0.5*(1+erf((x-mu)/(std*sqrt2))) — branchless A&S 7.1.26, |erf err|<=1.5e-7
__device__ __forceinline__ float laplacian_attn_fast(float x) {
  float z = (x - 0.70710678118654752f) * 0.79788456080286536f;
  float az = fabsf(z);
  float t = __builtin_amdgcn_rcpf(fmaf(0.3275911f, az, 1.0f));
  float p = fmaf(t, 1.061405429f, -1.453152027f);
  p = fmaf(t, p, 1.421413741f);
  p = fmaf(t, p, -0.284496736f);
  p = fmaf(t, p, 0.254829592f);
  p = p * t;
  float e = __expf(-az * az);
  float em = 1.0f - p * e;                  // erf(|z|)
  float er = (z < 0.0f) ? -em : em;         // erf(z)
  return fmaf(0.5f, er, 0.5f);
}

// ---- wave-private 64x64 GEMM on TILED operands, register pipeline ---------
// A tiled [RA][K] row-blocks rbA..+3, Bt tiled [RB][K] row-blocks rbB..+3.
// KBa/KBb = K>>5. nkb even, >=2. Fragments global->VGPR, contiguous 16B/lane.
__device__ __forceinline__ void wave_gemm_r(
    const uint16_t* __restrict__ A, int KBa, int rbA,
    const uint16_t* __restrict__ Bt, int KBb, int rbB,
    int nkb, f32x4 acc[4][4])
{
  const int lane = threadIdx.x & 63;

  const uint16_t* pa[4];
  const uint16_t* pb[4];
  #pragma unroll
  for (int mt = 0; mt < 4; mt++)
    pa[mt] = A + (size_t)(rbA + mt) * KBa * 512 + lane * 8;
  #pragma unroll
  for (int nt = 0; nt < 4; nt++)
    pb[nt] = Bt + (size_t)(rbB + nt) * KBb * 512 + lane * 8;

  #pragma unroll
  for (int mt = 0; mt < 4; mt++)
    #pragma unroll
    for (int nt = 0; nt < 4; nt++) {
      f32x4 z = {0.0f, 0.0f, 0.0f, 0.0f};
      acc[mt][nt] = z;
    }

  short8 fa0[4], fb0[4], fa1[4], fb1[4];

  auto loads = [&](short8 fa[4], short8 fb[4], int kb) {
    #pragma unroll
    for (int mt = 0; mt < 4; mt++)
      fa[mt] = *(const short8*)(pa[mt] + (size_t)kb * 512);
    #pragma unroll
    for (int nt = 0; nt < 4; nt++)
      fb[nt] = *(const short8*)(pb[nt] + (size_t)kb * 512);
  };
  auto mfmas = [&](short8 fa[4], short8 fb[4]) {
    #pragma unroll
    for (int mt = 0; mt < 4; mt++)
      #pragma unroll
      for (int nt = 0; nt < 4; nt++)
        acc[mt][nt] = __builtin_amdgcn_mfma_f32_16x16x32_bf16(
            fa[mt], fb[nt], acc[mt][nt], 0, 0, 0);
  };

  loads(fa0, fb0, 0);
  loads(fa1, fb1, 1);
  for (int kb = 2; kb < nkb; kb += 2) {
    mfmas(fa0, fb0);
    loads(fa0, fb0, kb);
    mfmas(fa1, fb1);
    loads(fa1, fb1, kb + 1);
  }
  mfmas(fa0, fb0);
  mfmas(fa1, fb1);
}

// 256-thread block = 4 independent waves over a 128x128 tile.
// wave w: rows +(w>>1)*64 (row-blocks +(w>>1)*4), cols +(w&1)*64.
#define WAVE_PREAMBLE                                  \
  int lane = threadIdx.x & 63;                         \
  int wave = threadIdx.x >> 6;                         \
  int lane16 = lane & 15;                              \
  int quad = lane >> 4;                                \
  int wrow = (wave >> 1) * 64;                         \
  int wcol = (wave & 1) * 64;

// ---- prep kernels ----------------------------------------------------------

// x fp32 [8192][1024] -> xb TILED bf16. Reads linear/coalesced (32B/lane),
// writes scattered 16B into tiles (L2 write-combines).
__global__ __launch_bounds__(256) void k_prep_x(
    const float* __restrict__ x, uint16_t* __restrict__ xb)
{
  int t = blockIdx.x * 256 + threadIdx.x;      // 0 .. 8192*128-1
  int i  = t >> 7;                             // row
  int k0 = (t & 127) * 8;                      // k-octet start
  const float* src = x + (size_t)t * 8;
  float4 a = *(const float4*)src;
  float4 b = *(const float4*)(src + 4);
  short8 o;
  o[0] = f32_to_bf16(a.x); o[1] = f32_to_bf16(a.y);
  o[2] = f32_to_bf16(a.z); o[3] = f32_to_bf16(a.w);
  o[4] = f32_to_bf16(b.x); o[5] = f32_to_bf16(b.y);
  o[6] = f32_to_bf16(b.z); o[7] = f32_to_bf16(b.w);
  size_t dst = ((size_t)(i >> 4) * 32 + (k0 >> 5)) * 512 +
               ((k0 >> 3) & 3) * 128 + (i & 15) * 8;
  *(short8*)(xb + dst) = o;
}

// wqk [1024][128], wv [1024][1024] fp32 -> wT TILED bf16, rows n=0..1151
__global__ __launch_bounds__(256) void k_prep_w(
    const float* __restrict__ wqk, const float* __restrict__ wv,
    uint16_t* __restrict__ wT)
{
  int t = blockIdx.x * 256 + threadIdx.x;      // 0 .. 1152*128-1
  int n16 = t & 15, oct = (t >> 4) & 3, kb = (t >> 6) & 31, nb = t >> 11;
  int n = nb * 16 + n16;
  int k0 = kb * 32 + oct * 8;
  short8 o;
  if (n < DQK) {
    #pragma unroll
    for (int j = 0; j < 8; j++)
      o[j] = f32_to_bf16(wqk[(size_t)(k0 + j) * DQK + n]);
  } else {
    int nn = n - DQK;
    #pragma unroll
    for (int j = 0; j < 8; j++)
      o[j] = f32_to_bf16(wv[(size_t)(k0 + j) * DV + nn]);
  }
  *(short8*)(wT + (size_t)t * 8) = o;
}

// bias_n[n] = rel_bias[bucket(n)] * sqrt(DQK)
__global__ __launch_bounds__(256) void k_bias(
    const float* __restrict__ rel, float* __restrict__ bias_n)
{
  int n = blockIdx.x * blockDim.x + threadIdx.x;
  if (n >= S_) return;
  int bucket;
  if (n < 16) {
    bucket = n;
  } else {
    float tt = logf((float)n * 0.0625f) / 2.0794415416798357f * 16.0f;
    int vl = 16 + (int)tt;
    bucket = vl < 31 ? vl : 31;
  }
  bias_n[n] = rel[bucket] * 11.313708498984761f;
}

// ---- GEMM kernels ----------------------------------------------------------

// fused projections. grid (9, 64). bx==0 -> q/k epilogue; bx>=1 -> v -> vT.
__global__ __launch_bounds__(256, 3) void k_gemm_qkv(
    const uint16_t* __restrict__ xb, const uint16_t* __restrict__ wT,
    const float* __restrict__ bqk, const float* __restrict__ gamma,
    const float* __restrict__ beta, const float* __restrict__ bv,
    uint16_t* __restrict__ qb, uint16_t* __restrict__ kb,
    uint16_t* __restrict__ vT)
{
  int bx = blockIdx.x, by = blockIdx.y;
  WAVE_PREAMBLE
  f32x4 acc[4][4];
  wave_gemm_r(xb, DIM_ >> 5, by * 8 + (wave >> 1) * 4,
              wT, DIM_ >> 5, bx * 8 + (wave & 1) * 4,
              DIM_ >> 5, acc);

  if (bx == 0) {
    #pragma unroll
    for (int nt = 0; nt < 4; nt++) {
      int col = wcol + nt * 16 + lane16;           // 0..127
      float bb = bqk[col];
      float g0 = gamma[col], b0 = beta[col];
      float g1 = gamma[DQK + col], b1 = beta[DQK + col];
      int coff = (col >> 5) * 512 + ((col >> 3) & 3) * 128 + (col & 7);
      #pragma unroll
      for (int mt = 0; mt < 4; mt++) {
        int rb = by * 8 + (wave >> 1) * 4 + mt;    // row-block, KB=4
        size_t base = (size_t)rb * 4 * 512 + coff + (size_t)(quad * 4) * 8;
        #pragma unroll
        for (int r = 0; r < 4; r++) {
          float s = silu_f(acc[mt][nt][r] + bb);
          qb[base + r * 8] = f32_to_bf16(s * g0 + b0);
          kb[base + r * 8] = f32_to_bf16(s * g1 + b1);
        }
      }
    }
  } else {
    int b = by >> 4;                               // batch (by*128 / 2048)
    uint16_t* vt = vT + (size_t)b * DV * S_;
    #pragma unroll
    for (int nt = 0; nt < 4; nt++) {
      int n = (bx - 1) * 128 + wcol + nt * 16 + lane16;   // 0..1023
      float bb = bv[n];
      #pragma unroll
      for (int mt = 0; mt < 4; mt++) {
        int j0l = (by & 15) * 128 + wrow + mt * 16 + quad * 4; // local seq
        uint16_t v0 = f32_to_bf16(silu_f(acc[mt][nt][0] + bb));
        uint16_t v1 = f32_to_bf16(silu_f(acc[mt][nt][1] + bb));
        uint16_t v2 = f32_to_bf16(silu_f(acc[mt][nt][2] + bb));
        uint16_t v3 = f32_to_bf16(silu_f(acc[mt][nt][3] + bb));
        size_t off = (size_t)((n >> 4) * 64 + (j0l >> 5)) * 512 +
                     ((j0l >> 3) & 3) * 128 + (n & 15) * 8 + (j0l & 7);
        uint2 pk;
        pk.x = (uint32_t)v0 | ((uint32_t)v1 << 16);
        pk.y = (uint32_t)v2 | ((uint32_t)v3 << 16);
        *(uint2*)(vt + off) = pk;
      }
    }
  }
}

// attn = laplacian(q@k^T/S + bias[i-j]) causal, TILED bf16 per batch.
// grid (16, 16, 4): jt, it, b; jt>it skipped (tiles never read downstream).
__global__ __launch_bounds__(256, 3) void k_gemm_sim(
    const uint16_t* __restrict__ qb, const uint16_t* __restrict__ kb,
    const float* __restrict__ bias_n, uint16_t* __restrict__ attn)
{
  int jt = blockIdx.x, it = blockIdx.y, bt = blockIdx.z;
  if (jt > it) return;
  WAVE_PREAMBLE
  f32x4 acc[4][4];
  wave_gemm_r(qb, 4, bt * 128 + it * 8 + (wave >> 1) * 4,
              kb, 4, bt * 128 + jt * 8 + (wave & 1) * 4,
              4, acc);
  uint16_t* ab = attn + (size_t)bt * S_ * S_;
  #pragma unroll
  for (int nt = 0; nt < 4; nt++) {
    int j = jt * 128 + wcol + nt * 16 + lane16;
    size_t joff = (size_t)(j >> 5) * 512 + ((j >> 3) & 3) * 128 + (j & 7);
    #pragma unroll
    for (int mt = 0; mt < 4; mt++) {
      #pragma unroll
      for (int r = 0; r < 4; r++) {
        int i = it * 128 + wrow + mt * 16 + quad * 4 + r;
        float aval = 0.0f;
        if (j <= i) {
          float sim = acc[mt][nt][r] * (1.0f / 2048.0f) + bias_n[i - j];
          aval = laplacian_attn_fast(sim);
        }
        ab[(size_t)(i >> 4) * 64 * 512 + joff + (size_t)(i & 15) * 8] =
            f32_to_bf16(aval);
      }
    }
  }
}

// out = attn @ v, fp32 out. grid (8, 64): y = bt*16 + tt, it balanced so
// co-resident groups get ~constant K; nkb = 4*it+4 (causal bound).
__global__ __launch_bounds__(256, 3) void k_gemm_out(
    const uint16_t* __restrict__ attn, const uint16_t* __restrict__ vT,
    float* __restrict__ out)
{
  int nx = blockIdx.x;
  int y = blockIdx.y;
  int bt = y >> 4, tt = y & 15;
  int it = (bt & 1) ? (15 - tt) : tt;
  int nkb = 4 * it + 4;
  WAVE_PREAMBLE
  f32x4 acc[4][4];
  wave_gemm_r(attn + (size_t)bt * S_ * S_, 64, it * 8 + (wave >> 1) * 4,
              vT + (size_t)bt * DV * S_, 64, nx * 8 + (wave & 1) * 4,
              nkb, acc);
  #pragma unroll
  for (int mt = 0; mt < 4; mt++)
    #pragma unroll
    for (int nt = 0; nt < 4; nt++)
      #pragma unroll
      for (int r = 0; r < 4; r++) {
        int i = it * 128 + wrow + mt * 16 + quad * 4 + r;
        int n = nx * 128 + wcol + nt * 16 + lane16;
        out[((size_t)bt * S_ + i) * DV + n] = acc[mt][nt][r];
      }
}

// ---------------------------------------------------------------------------

extern "C" void kernel_launch(void* const* d_in, const int* in_sizes, int n_in,
                              void* d_out, int out_size, void* d_ws, size_t ws_size,
                              hipStream_t stream)
{
  const float* x     = (const float*)d_in[0];
  const float* wqk   = (const float*)d_in[1];
  const float* bqk   = (const float*)d_in[2];
  const float* gamma = (const float*)d_in[3];
  const float* beta  = (const float*)d_in[4];
  const float* wv    = (const float*)d_in[5];
  const float* bv    = (const float*)d_in[6];
  const float* rel   = (const float*)d_in[7];
  float* out = (float*)d_out;

  char* ws = (char*)d_ws;
  size_t off = 0;
  uint16_t* xb     = (uint16_t*)(ws + off); off += (size_t)B_ * S_ * DIM_ * 2;  // 16 MB
  uint16_t* wT     = (uint16_t*)(ws + off); off += (size_t)NQV * DIM_ * 2;      // 2.25 MB
  uint16_t* qb     = (uint16_t*)(ws + off); off += (size_t)B_ * S_ * DQK * 2;   // 2 MB
  uint16_t* kb     = (uint16_t*)(ws + off); off += (size_t)B_ * S_ * DQK * 2;   // 2 MB
  uint16_t* vT     = (uint16_t*)(ws + off); off += (size_t)B_ * DV * S_ * 2;    // 16 MB
  uint16_t* attn   = (uint16_t*)(ws + off); off += (size_t)B_ * S_ * S_ * 2;    // 32 MB
  float*    bias_n = (float*)(ws + off);    off += (size_t)S_ * 4;              // 8 KB

  k_prep_x<<<dim3(B_ * S_ * DIM_ / 8 / 256), dim3(256), 0, stream>>>(x, xb);
  k_prep_w<<<dim3(NQV * DIM_ / 8 / 256), dim3(256), 0, stream>>>(wqk, wv, wT);
  k_bias<<<dim3(S_ / 256), dim3(256), 0, stream>>>(rel, bias_n);

  k_gemm_qkv<<<dim3(NQV / 128, B_ * S_ / 128), dim3(256), 0, stream>>>(
      xb, wT, bqk, gamma, beta, bv, qb, kb, vT);
  k_gemm_sim<<<dim3(S_ / 128, S_ / 128, B_), dim3(256), 0, stream>>>(
      qb, kb, bias_n, attn);
  k_gemm_out<<<dim3(DV / 128, B_ * S_ / 128), dim3(256), 0, stream>>>(
      attn, vT, out);
}